// Round 14
// baseline (108.851 us; speedup 1.0000x reference)
//
#include <hip/hip_runtime.h>

// ---------------------------------------------------------------------------
// SwitchHeadAttention: x@Wq -> Q, x@Wkv -> K,V ; flash attention ; per-head
// output projection with Wo + bo.  B=2 T=2048 DIM=1024 H=16 DH=64.
// R14: qkv_gemm V-epilogue coalescing: V-blocks transpose acc through LDS
//      (per-wave 8KB region aliasing As/Bs, 16B-XOR swizzle) and store V^T
//      rows as full 128B coalesced dwordx4 (was 8B/lane at 4KB stride = 25%
//      sector efficiency).  attn frozen at R13 (single-barrier protocol).
// ---------------------------------------------------------------------------

typedef __attribute__((ext_vector_type(8))) short bf16x8;
typedef __attribute__((ext_vector_type(4))) float f32x4;
typedef __attribute__((ext_vector_type(16))) float f32x16;

#define MFMA16(a, b, c) __builtin_amdgcn_mfma_f32_16x16x32_bf16((a), (b), (c), 0, 0, 0)
#define MFMA32(a, b, c) __builtin_amdgcn_mfma_f32_32x32x16_bf16((a), (b), (c), 0, 0, 0)

#define B_    2
#define T_    2048
#define DIM_  1024
#define H_    16
#define DH_   64

__device__ inline unsigned short f2bf(float x) {
    union { float f; unsigned int u; } c; c.f = x;
    unsigned int r = c.u + 0x7FFFu + ((c.u >> 16) & 1u);   // RNE
    return (unsigned short)(r >> 16);
}

__device__ __forceinline__ void gll16(const void* g, void* l) {
    __builtin_amdgcn_global_load_lds(
        (const __attribute__((address_space(1))) void*)g,
        (__attribute__((address_space(3))) void*)l, 16, 0, 0);
}

// -------------------- convert x (fp32 -> bf16), 4 elems/thread -------------
__global__ __launch_bounds__(256) void cvt_x_kernel(const float* __restrict__ x,
                                                    unsigned short* __restrict__ xb,
                                                    int n4) {
    int i = blockIdx.x * 256 + threadIdx.x;
    if (i >= n4) return;
    const float4 v = reinterpret_cast<const float4*>(x)[i];
    union { unsigned short h[4]; uint2 u; } o;
    o.h[0] = f2bf(v.x); o.h[1] = f2bf(v.y); o.h[2] = f2bf(v.z); o.h[3] = f2bf(v.w);
    reinterpret_cast<uint2*>(xb)[i] = o.u;
}

// ------------- transpose + convert weights: src[R][C] -> dst[C][R] ---------
__global__ __launch_bounds__(256) void transpose_cvt_kernel(const float* __restrict__ src,
                                                            unsigned short* __restrict__ dst,
                                                            int R, int C, float scale) {
    __shared__ float tile[32][33];
    int bc = blockIdx.x * 32, br = blockIdx.y * 32;
    int tx = threadIdx.x & 31, ty = threadIdx.x >> 5;   // 32 x 8
    for (int i = ty; i < 32; i += 8)
        tile[i][tx] = src[(size_t)(br + i) * C + bc + tx];
    __syncthreads();
    for (int i = ty; i < 32; i += 8)
        dst[(size_t)(bc + i) * R + br + tx] = f2bf(tile[tx][i] * scale);
}

// --------- Wo[h][d][e] -> WoT[h][e][d] bf16 (65536 elements) ---------------
__global__ __launch_bounds__(256) void cvt_wo_kernel(const float* __restrict__ wo,
                                                     unsigned short* __restrict__ wot) {
    int i = blockIdx.x * 256 + threadIdx.x;          // i = h*4096 + e*64 + d
    int h = i >> 12, e = (i >> 6) & 63, d = i & 63;
    wot[i] = f2bf(wo[(h << 12) + (d << 6) + e]);
}

// -------------------- fused QKV GEMM:  [4096x1024] @ [1024x3072] -----------
// A = xb row-major, B = wt[n][k].  Tile 128x128, BK=64.  Staging via
// global_load_lds width=16 (linear LDS dest, inverse-swizzled global src).
// V-blocks (bn>=2048) transpose acc through LDS and store V^T coalesced.
__global__ __launch_bounds__(256) void qkv_gemm_kernel(const unsigned short* __restrict__ xb,
                                                       const unsigned short* __restrict__ wt,
                                                       unsigned short* __restrict__ qb,
                                                       unsigned short* __restrict__ kb,
                                                       unsigned short* __restrict__ vt) {
    __shared__ __align__(16) unsigned short smem[16384];   // As[128][64] | Bs[128][64]
    unsigned short* As = smem;
    unsigned short* Bs = smem + 8192;

    const int tid  = threadIdx.x;
    const int lane = tid & 63, wv = tid >> 6;
    const int lr = lane & 15, lg = lane >> 4;
    const int bm = (int)(blockIdx.x & 31) * 128;   // 32 M-tiles
    const int bn = (int)(blockIdx.x >> 5) * 128;   // 24 N-tiles
    const int wm = (wv >> 1) * 64, wn = (wv & 1) * 64;
    const int sRow8 = lane >> 3, sSlot = lane & 7;

    f32x4 acc[4][4] = {};

    for (int k0 = 0; k0 < DIM_; k0 += 64) {
        __syncthreads();   // previous iteration's LDS reads done
#pragma unroll
        for (int pass = 0; pass < 4; ++pass) {
            int r = pass * 32 + wv * 8 + sRow8;
            int c = sSlot ^ (r & 7);   // inverse-swizzle source chunk
            gll16(xb + (size_t)(bm + r) * DIM_ + k0 + c * 8, As + (pass * 32 + wv * 8) * 64);
            gll16(wt + (size_t)(bn + r) * DIM_ + k0 + c * 8, Bs + (pass * 32 + wv * 8) * 64);
        }
        asm volatile("s_waitcnt vmcnt(0)" ::: "memory");
        __syncthreads();

        bf16x8 a[4][2], b[4][2];
#pragma unroll
        for (int mi = 0; mi < 4; mi++)
#pragma unroll
            for (int ks = 0; ks < 2; ks++) {
                int row = wm + mi * 16 + lr;
                a[mi][ks] = *reinterpret_cast<const bf16x8*>(
                    As + row * 64 + ((ks * 4 + lg) ^ (lr & 7)) * 8);
            }
#pragma unroll
        for (int nj = 0; nj < 4; nj++)
#pragma unroll
            for (int ks = 0; ks < 2; ks++) {
                int row = wn + nj * 16 + lr;
                b[nj][ks] = *reinterpret_cast<const bf16x8*>(
                    Bs + row * 64 + ((ks * 4 + lg) ^ (lr & 7)) * 8);
            }
        __builtin_amdgcn_s_setprio(1);
#pragma unroll
        for (int ks = 0; ks < 2; ks++)
#pragma unroll
            for (int mi = 0; mi < 4; mi++)
#pragma unroll
                for (int nj = 0; nj < 4; nj++)
                    acc[mi][nj] = MFMA16(a[mi][ks], b[nj][ks], acc[mi][nj]);
        __builtin_amdgcn_s_setprio(0);
    }

    if (bn < 2048) {
        // ---- Q/K epilogue (unchanged): 32B-sector-efficient scalar stores --
#pragma unroll
        for (int mi = 0; mi < 4; mi++) {
            int m  = bm + wm + mi * 16 + lg * 4;   // row for rr=0
            int bb = m >> 11, t = m & 2047;
#pragma unroll
            for (int nj = 0; nj < 4; nj++) {
                int n = bn + wn + nj * 16 + lr;
                unsigned short* dst = (n < 1024) ? qb : kb;
                int n2 = n & 1023;
                int h = n2 >> 6, d = n2 & 63;
                size_t base = ((size_t)((bb << 4) + h) * T_ + t) * DH_ + d;
#pragma unroll
                for (int rr = 0; rr < 4; rr++)
                    dst[base + (size_t)rr * DH_] = f2bf(acc[mi][nj][rr]);
            }
        }
    } else {
        // ---- V epilogue: LDS transpose -> coalesced V^T row stores --------
        __syncthreads();   // all K-loop As/Bs reads retired before overwrite
        unsigned short* Vw = smem + wv * 4096;   // per-wave [64 d][64 t], XOR-swz

        // write acc -> Vw: t-chunk c (8B = 4 t) at swizzled pair position
#pragma unroll
        for (int mi = 0; mi < 4; mi++)
#pragma unroll
            for (int nj = 0; nj < 4; nj++) {
                int dl = nj * 16 + lr;                 // local d
                int c  = mi * 4 + lg;                  // 8B chunk idx (0..15)
                int cs = (((c >> 1) ^ (dl & 7)) << 1) | (c & 1);   // 16B-pair XOR
                union { unsigned short h4[4]; uint2 u; } pk;
#pragma unroll
                for (int rr = 0; rr < 4; rr++) pk.h4[rr] = f2bf(acc[mi][nj][rr]);
                *reinterpret_cast<uint2*>(Vw + dl * 64 + cs * 4) = pk.u;
            }
        asm volatile("s_waitcnt lgkmcnt(0)" ::: "memory");   // same-wave RAW
        __builtin_amdgcn_sched_barrier(0);

        // read back 16B units (pair (2k,2k+1) lives at 16B slot k^e) and
        // store V^T rows: 8 rows x 128B per instruction, fully coalesced.
        const int h  = (bn - 2048 + wn) >> 6;
        const int mb = bm + wm;
        const int bb = mb >> 11, tb = mb & 2047;
        const size_t rowbase = ((size_t)((bb << 4) + h) * DH_) * T_;
#pragma unroll
        for (int g = 0; g < 8; ++g) {
            int dl = g * 8 + (lane >> 3);
            int k  = lane & 7;
            bf16x8 v = *reinterpret_cast<const bf16x8*>(
                Vw + dl * 64 + ((k ^ (dl & 7)) << 3));
            *reinterpret_cast<int4*>(vt + rowbase + (size_t)dl * T_ + tb + k * 8) =
                *reinterpret_cast<const int4*>(&v);
        }
    }
}

// -------------------- flash attention + fused output projection ------------
// grid = B*H*(T/64) = 1024 blocks; 4 waves = 2 q-waves(32 rows) x 2 key-grps.
// Scores in exp2 domain (LOG2E folded into Wq).  Static softmax (m=0).
// Double buffer, ONE barrier per KV tile + one post-loop barrier.
__global__ __launch_bounds__(256, 4) void attn_kernel(const unsigned short* __restrict__ qb,
                                                      const unsigned short* __restrict__ kbp,
                                                      const unsigned short* __restrict__ vt,
                                                      const unsigned short* __restrict__ wot,
                                                      const float* __restrict__ bo,
                                                      float* __restrict__ out) {
    // LDS map (bytes):
    //   [0,16384)     buf0: Ks[64][64] (8K) + Vs[64][64] (8K)
    //   [16384,32768) buf1: same
    //   epilogue aliases (all writes AFTER the post-loop barrier):
    //     Oex f32[2][32][64] @0 ; Olds bf16[2][32][64] @16384 ;
    //     Ls f32[2][32] @24576
    __shared__ __align__(16) char smem[32768];

    const int tid  = threadIdx.x;
    const int lane = tid & 63;
    const int wv   = tid >> 6;           // 0..3
    const int wq   = wv & 1, kg = wv >> 1;
    const int L    = lane & 31, hh = lane >> 5;
    const int kswz = L & 7;

    const int bid = (int)blockIdx.x;
    const int blk = (bid & 7) * 128 + (bid >> 3);  // XCD-chunked swizzle (1024/8)
    const int qt = blk & 31, bh = blk >> 5;        // 32 q-tiles of 64 rows
    const int b = bh >> 4, h = bh & 15;

    const unsigned short* Qp  = qb  + (size_t)bh * (T_ * DH_);
    const unsigned short* Kp  = kbp + (size_t)bh * (T_ * DH_);
    const unsigned short* Vtp = vt  + (size_t)bh * (DH_ * T_);

    // ---- Q fragments (B-operand: n=q=L, k = 16kc+8hh+j) ----
    const int qrow0 = qt * 64 + wq * 32;
    bf16x8 qf[4];
#pragma unroll
    for (int kc = 0; kc < 4; ++kc)
        qf[kc] = *reinterpret_cast<const bf16x8*>(
            Qp + (size_t)(qrow0 + L) * DH_ + kc * 16 + hh * 8);

    // ---- staging: all 4 waves; K rows wv*16..+16, V d-rows wv*16..+16 ----
    auto stage = [&](int bufsel, int kt0) {
        char* base = smem + bufsel * 16384;
        const int r8 = lane >> 3;
        const int c  = (lane & 7) ^ r8;       // row&7 == r8 for all rows below
#pragma unroll
        for (int g = 0; g < 2; ++g) {
            int row = wv * 16 + g * 8 + r8;   // K: key row
            gll16(Kp + ((size_t)(kt0 + row) << 6) + (c << 3),
                  base + (wv * 16 + g * 8) * 128);
        }
#pragma unroll
        for (int g = 0; g < 2; ++g) {
            int d = wv * 16 + g * 8 + r8;     // V: d row
            gll16(Vtp + ((size_t)d << 11) + kt0 + (c << 3),
                  base + 8192 + (wv * 16 + g * 8) * 128);
        }
    };

    f32x16 o0 = {}, o1 = {};
    float lpv[4] = {0.f, 0.f, 0.f, 0.f};   // 4-way partial row-sum

    stage(0, 0);   // prologue: tile 0 in flight

    const int NT = T_ / 64;   // 32 tiles
    for (int it = 0; it < NT; ++it) {
        const int cur = it & 1;
        // vmcnt(0): stage(it)'s loads (issued a full iteration ago) landed.
        // lgkmcnt(0): this wave's ds_reads of the buffer about to be restaged
        // retired (rule #18 guard for the single-barrier protocol).
        asm volatile("s_waitcnt vmcnt(0) lgkmcnt(0)" ::: "memory");
        __builtin_amdgcn_sched_barrier(0);
        __builtin_amdgcn_s_barrier();
        __builtin_amdgcn_sched_barrier(0);

        if (it + 1 < NT)   // stage tile it+1 into the buffer read at it-1;
            stage(cur ^ 1, (it + 1) * 64);   // its loads fly under compute

        const char* KB = smem + cur * 16384;
        const char* VB = KB + 8192;

        // ---- S^T = K * Q^T  (this key-group's 32 keys) ----
        f32x16 s = {};
        __builtin_amdgcn_s_setprio(1);
#pragma unroll
        for (int kc = 0; kc < 4; ++kc) {
            bf16x8 ka = *reinterpret_cast<const bf16x8*>(
                KB + (kg * 32 + L) * 128 + (((kc * 2 + hh) ^ kswz) << 4));
            s = MFMA32(ka, qf[kc], s);
        }
        __builtin_amdgcn_s_setprio(0);

        // ---- static softmax: P = exp2(S); partial row-sums ----
#pragma unroll
        for (int r = 0; r < 16; ++r) {
            s[r] = __builtin_amdgcn_exp2f(s[r]);
            lpv[r & 3] += s[r];
        }

        // ---- pack P to A-frags (cvt_pk + permlane32_swap), PV MFMAs ----
        __builtin_amdgcn_s_setprio(1);
#pragma unroll
        for (int kc = 0; kc < 2; ++kc) {
            unsigned X, X2, Y, Y2;
            asm("v_cvt_pk_bf16_f32 %0, %1, %2" : "=v"(X)  : "v"(s[kc * 8 + 0]), "v"(s[kc * 8 + 1]));
            asm("v_cvt_pk_bf16_f32 %0, %1, %2" : "=v"(X2) : "v"(s[kc * 8 + 2]), "v"(s[kc * 8 + 3]));
            asm("v_cvt_pk_bf16_f32 %0, %1, %2" : "=v"(Y)  : "v"(s[kc * 8 + 4]), "v"(s[kc * 8 + 5]));
            asm("v_cvt_pk_bf16_f32 %0, %1, %2" : "=v"(Y2) : "v"(s[kc * 8 + 6]), "v"(s[kc * 8 + 7]));
            asm("v_permlane32_swap_b32 %0, %1" : "+v"(X),  "+v"(Y));
            asm("v_permlane32_swap_b32 %0, %1" : "+v"(X2), "+v"(Y2));
            union { unsigned w[4]; bf16x8 v; } pa;
            pa.w[0] = X; pa.w[1] = X2; pa.w[2] = Y; pa.w[3] = Y2;
            const int gc = kg * 4 + kc * 2 + hh;   // key chunk (of 8)
            bf16x8 vf0 = *reinterpret_cast<const bf16x8*>(
                VB + L * 128 + ((gc ^ kswz) << 4));
            bf16x8 vf1 = *reinterpret_cast<const bf16x8*>(
                VB + (32 + L) * 128 + ((gc ^ kswz) << 4));
            o0 = MFMA32(pa.v, vf0, o0);
            o1 = MFMA32(pa.v, vf1, o1);
        }
        __builtin_amdgcn_s_setprio(0);
        // no trailing barrier: next iteration's barrier closes the phase
    }

    // ---- POST-LOOP BARRIER: all waves' iter-31 LDS reads must retire before
    // the epilogue overwrites buf regions (Ls aliases buf1's V).
    asm volatile("s_waitcnt vmcnt(0) lgkmcnt(0)" ::: "memory");
    __builtin_amdgcn_sched_barrier(0);
    __builtin_amdgcn_s_barrier();
    __builtin_amdgcn_sched_barrier(0);

    // ---- epilogue: combine key-groups, normalize, Y = O@Wo + bo ----
    float lp = (lpv[0] + lpv[1]) + (lpv[2] + lpv[3]);
    float l2 = lp + __shfl_xor(lp, 32);          // hh-combine: kg row-sum

    float* Oex = (float*)smem;                              // [2][32][64] (buf0)
    unsigned short* Olds = (unsigned short*)(smem + 16384); // [2][32][64] (buf1)
    float* Ls = (float*)(smem + 24576);                     // [2][32]

    if (kg == 1) {
        if (lane < 32) Ls[wq * 32 + L] = l2;
#pragma unroll
        for (int g = 0; g < 4; ++g)
#pragma unroll
            for (int c = 0; c < 4; ++c) {
                int qr = c + 8 * g + 4 * hh;
                Oex[(wq * 32 + qr) * 64 + L]      = o0[g * 4 + c];
                Oex[(wq * 32 + qr) * 64 + 32 + L] = o1[g * 4 + c];
            }
    }
    asm volatile("s_waitcnt lgkmcnt(0)" ::: "memory");
    __builtin_amdgcn_sched_barrier(0);
    __builtin_amdgcn_s_barrier();
    __builtin_amdgcn_sched_barrier(0);
    if (kg == 1) return;

    // Wo^T B-fragments straight from global (L2-hot: 8KB/head x 32 blocks)
    bf16x8 wf0[4], wf1[4];
#pragma unroll
    for (int kc = 0; kc < 4; ++kc) {
        int ko = (kc * 2 + hh) * 8;
        wf0[kc] = *reinterpret_cast<const bf16x8*>(
            wot + ((size_t)h << 12) + (L << 6) + ko);
        wf1[kc] = *reinterpret_cast<const bf16x8*>(
            wot + ((size_t)h << 12) + ((32 + L) << 6) + ko);
    }

    float ltot = l2 + Ls[wq * 32 + L];
    float invq = 1.f / ltot;
    if (lane < 32) Ls[wq * 32 + L] = invq;       // same-wave DS in-order

    // combine + normalize -> Olds (bf16, XOR-swizzled rows for A-frag reads)
#pragma unroll
    for (int g = 0; g < 4; ++g)
#pragma unroll
        for (int c = 0; c < 4; ++c) {
            int qr = c + 8 * g + 4 * hh;
            float ir = Ls[wq * 32 + qr];
            float v0 = (o0[g * 4 + c] + Oex[(wq * 32 + qr) * 64 + L]) * ir;
            float v1 = (o1[g * 4 + c] + Oex[(wq * 32 + qr) * 64 + 32 + L]) * ir;
            int c0 = (L >> 3) ^ (qr & 7);
            int c1 = (4 + (L >> 3)) ^ (qr & 7);
            Olds[(wq * 32 + qr) * 64 + c0 * 8 + (L & 7)] = f2bf(v0);
            Olds[(wq * 32 + qr) * 64 + c1 * 8 + (L & 7)] = f2bf(v1);
        }

    // Y = O @ Wo[h]  (A = O from Olds, B = Wo^T frags from global)
    f32x16 y0 = {}, y1 = {};
    const char* OB = (const char*)(smem + 16384) + wq * 4096;
#pragma unroll
    for (int kc = 0; kc < 4; ++kc) {
        int ch = ((kc * 2 + hh) ^ kswz) << 4;
        bf16x8 oa = *reinterpret_cast<const bf16x8*>(OB + L * 128 + ch);
        y0 = MFMA32(oa, wf0[kc], y0);
        y1 = MFMA32(oa, wf1[kc], y1);
    }

    float bias0 = bo[(h << 6) + L];
    float bias1 = bo[(h << 6) + 32 + L];
#pragma unroll
    for (int g = 0; g < 4; ++g)
#pragma unroll
        for (int c = 0; c < 4; ++c) {
            int t = qrow0 + c + 8 * g + 4 * hh;
            float* op = out + ((size_t)(b * T_ + t) << 10) + (h << 6);
            op[L]      = y0[g * 4 + c] + bias0;
            op[32 + L] = y1[g * 4 + c] + bias1;
        }
}

// ---------------------------------------------------------------------------
extern "C" void kernel_launch(void* const* d_in, const int* in_sizes, int n_in,
                              void* d_out, int out_size, void* d_ws, size_t ws_size,
                              hipStream_t stream) {
    const float* x   = (const float*)d_in[0];
    const float* Wq  = (const float*)d_in[1];
    const float* Wkv = (const float*)d_in[2];
    const float* Wo  = (const float*)d_in[3];
    const float* bo  = (const float*)d_in[4];
    float* out = (float*)d_out;

    char* ws = (char*)d_ws;
    unsigned short* xb  = (unsigned short*)(ws);                  //  8 MB  x bf16
    unsigned short* wt  = (unsigned short*)(ws + 8388608);        //  6 MB  [Wq^T;Wkv^T]
    unsigned short* wot = (unsigned short*)(ws + 14680064);       // 128 KB Wo^T
    unsigned short* qb  = (unsigned short*)(ws + 14811136);       //  8 MB  Q   [b][h][t][d]
    unsigned short* kb  = (unsigned short*)(ws + 23199744);       //  8 MB  K   [b][h][t][d]
    unsigned short* vt  = (unsigned short*)(ws + 31588352);       //  8 MB  V^T [b][h][d][t]

    cvt_x_kernel<<<4096, 256, 0, stream>>>(x, xb, (B_ * T_ * DIM_) / 4);
    // Wq cols pre-scaled by DH^-0.5 * log2(e) (softmax runs in exp2 domain)
    transpose_cvt_kernel<<<dim3(32, 32), 256, 0, stream>>>(Wq, wt, DIM_, 1024, 0.125f * 1.44269504089f);
    transpose_cvt_kernel<<<dim3(64, 32), 256, 0, stream>>>(Wkv, wt + 1024 * 1024, DIM_, 2048, 1.0f);
    cvt_wo_kernel<<<256, 256, 0, stream>>>(Wo, wot);
    qkv_gemm_kernel<<<768, 256, 0, stream>>>(xb, wt, qb, kb, vt);
    attn_kernel<<<1024, 256, 0, stream>>>(qb, kb, vt, wot, bo, out);
}

// Round 15
// 94.875 us; speedup vs baseline: 1.1473x; 1.1473x over previous
//
#include <hip/hip_runtime.h>

// ---------------------------------------------------------------------------
// SwitchHeadAttention: x@Wq -> Q, x@Wkv -> K,V ; flash attention ; per-head
// output projection with Wo + bo.  B=2 T=2048 DIM=1024 H=16 DH=64.
// R15: R14's V-epilogue reverted (L2 write-combining already merged the old
//      scattered stores; LDS transpose was pure overhead, +7us).  gemm/attn
//      = R13 exactly (102.0us known good).  NEW: the four prep kernels
//      (cvt_x, Wq^T, Wkv^T, Wo^T) fused into ONE grid-sectioned launch so
//      the small converts run concurrently instead of serially with gaps.
// ---------------------------------------------------------------------------

typedef __attribute__((ext_vector_type(8))) short bf16x8;
typedef __attribute__((ext_vector_type(4))) float f32x4;
typedef __attribute__((ext_vector_type(16))) float f32x16;

#define MFMA16(a, b, c) __builtin_amdgcn_mfma_f32_16x16x32_bf16((a), (b), (c), 0, 0, 0)
#define MFMA32(a, b, c) __builtin_amdgcn_mfma_f32_32x32x16_bf16((a), (b), (c), 0, 0, 0)

#define B_    2
#define T_    2048
#define DIM_  1024
#define H_    16
#define DH_   64

__device__ inline unsigned short f2bf(float x) {
    union { float f; unsigned int u; } c; c.f = x;
    unsigned int r = c.u + 0x7FFFu + ((c.u >> 16) & 1u);   // RNE
    return (unsigned short)(r >> 16);
}

__device__ __forceinline__ void gll16(const void* g, void* l) {
    __builtin_amdgcn_global_load_lds(
        (const __attribute__((address_space(1))) void*)g,
        (__attribute__((address_space(3))) void*)l, 16, 0, 0);
}

// ---------------- fused prep: cvt_x | Wo^T | Wq^T | Wkv^T ------------------
// grid sections: [0,4096) cvt_x ; [4096,4352) cvt_wo ;
//                [4352,5376) Wq transpose 32x32 ; [5376,7424) Wkv 64x32.
__global__ __launch_bounds__(256) void prep_kernel(const float* __restrict__ x,
                                                   const float* __restrict__ Wq,
                                                   const float* __restrict__ Wkv,
                                                   const float* __restrict__ Wo,
                                                   unsigned short* __restrict__ xb,
                                                   unsigned short* __restrict__ wt,
                                                   unsigned short* __restrict__ wot) {
    __shared__ float tile[32][33];
    const int bid = (int)blockIdx.x;

    if (bid < 4096) {                       // ---- x fp32 -> bf16 (4/thread)
        int i = bid * 256 + threadIdx.x;
        const float4 v = reinterpret_cast<const float4*>(x)[i];
        union { unsigned short h[4]; uint2 u; } o;
        o.h[0] = f2bf(v.x); o.h[1] = f2bf(v.y); o.h[2] = f2bf(v.z); o.h[3] = f2bf(v.w);
        reinterpret_cast<uint2*>(xb)[i] = o.u;
        return;
    }
    if (bid < 4352) {                       // ---- Wo[h][d][e] -> WoT[h][e][d]
        int i = (bid - 4096) * 256 + threadIdx.x;
        int h = i >> 12, e = (i >> 6) & 63, d = i & 63;
        wot[i] = f2bf(Wo[(h << 12) + (d << 6) + e]);
        return;
    }
    // ---- weight transpose+cvt: src[R=1024][C] -> dst[C][1024] ----
    const float* src; unsigned short* dst; int C; float scale; int t;
    if (bid < 5376) {                       // Wq (pre-scaled DH^-0.5 * log2e)
        t = bid - 4352; src = Wq;  dst = wt;            C = 1024;
        scale = 0.125f * 1.44269504089f;
        // 32x32 grid: bx = t&31, by = t>>5
    } else {                                // Wkv
        t = bid - 5376; src = Wkv; dst = wt + 1024 * 1024; C = 2048;
        scale = 1.0f;
    }
    int bx, by;
    if (bid < 5376) { bx = t & 31; by = t >> 5; }
    else            { bx = t & 63; by = t >> 6; }
    int bc = bx * 32, br = by * 32;
    int tx = threadIdx.x & 31, ty = threadIdx.x >> 5;   // 32 x 8
    for (int i = ty; i < 32; i += 8)
        tile[i][tx] = src[(size_t)(br + i) * C + bc + tx];
    __syncthreads();
    for (int i = ty; i < 32; i += 8)
        dst[(size_t)(bc + i) * DIM_ + br + tx] = f2bf(tile[tx][i] * scale);
}

// -------------------- fused QKV GEMM:  [4096x1024] @ [1024x3072] -----------
// A = xb row-major, B = wt[n][k].  Tile 128x128, BK=64.  Staging via
// global_load_lds width=16 (linear LDS dest, inverse-swizzled global src).
__global__ __launch_bounds__(256) void qkv_gemm_kernel(const unsigned short* __restrict__ xb,
                                                       const unsigned short* __restrict__ wt,
                                                       unsigned short* __restrict__ qb,
                                                       unsigned short* __restrict__ kb,
                                                       unsigned short* __restrict__ vt) {
    __shared__ unsigned short As[128][64];
    __shared__ unsigned short Bs[128][64];
    const int tid  = threadIdx.x;
    const int lane = tid & 63, wv = tid >> 6;
    const int lr = lane & 15, lg = lane >> 4;
    const int bm = (int)(blockIdx.x & 31) * 128;   // 32 M-tiles
    const int bn = (int)(blockIdx.x >> 5) * 128;   // 24 N-tiles
    const int wm = (wv >> 1) * 64, wn = (wv & 1) * 64;
    const int sRow8 = lane >> 3, sSlot = lane & 7;

    f32x4 acc[4][4] = {};

    for (int k0 = 0; k0 < DIM_; k0 += 64) {
        __syncthreads();   // previous iteration's LDS reads done
#pragma unroll
        for (int pass = 0; pass < 4; ++pass) {
            int r = pass * 32 + wv * 8 + sRow8;
            int c = sSlot ^ (r & 7);   // inverse-swizzle source chunk
            gll16(xb + (size_t)(bm + r) * DIM_ + k0 + c * 8, &As[pass * 32 + wv * 8][0]);
            gll16(wt + (size_t)(bn + r) * DIM_ + k0 + c * 8, &Bs[pass * 32 + wv * 8][0]);
        }
        asm volatile("s_waitcnt vmcnt(0)" ::: "memory");
        __syncthreads();

        bf16x8 a[4][2], b[4][2];
#pragma unroll
        for (int mi = 0; mi < 4; mi++)
#pragma unroll
            for (int ks = 0; ks < 2; ks++) {
                int row = wm + mi * 16 + lr;
                a[mi][ks] = *reinterpret_cast<const bf16x8*>(
                    &As[row][((ks * 4 + lg) ^ (lr & 7)) * 8]);
            }
#pragma unroll
        for (int nj = 0; nj < 4; nj++)
#pragma unroll
            for (int ks = 0; ks < 2; ks++) {
                int row = wn + nj * 16 + lr;
                b[nj][ks] = *reinterpret_cast<const bf16x8*>(
                    &Bs[row][((ks * 4 + lg) ^ (lr & 7)) * 8]);
            }
        __builtin_amdgcn_s_setprio(1);
#pragma unroll
        for (int ks = 0; ks < 2; ks++)
#pragma unroll
            for (int mi = 0; mi < 4; mi++)
#pragma unroll
                for (int nj = 0; nj < 4; nj++)
                    acc[mi][nj] = MFMA16(a[mi][ks], b[nj][ks], acc[mi][nj]);
        __builtin_amdgcn_s_setprio(0);
    }

    // epilogue: m -> (b,t); n -> {Q,K,V} x (h,d)
#pragma unroll
    for (int mi = 0; mi < 4; mi++) {
        int m  = bm + wm + mi * 16 + lg * 4;   // row for rr=0 (multiple of 4)
        int bb = m >> 11, t = m & 2047;
#pragma unroll
        for (int nj = 0; nj < 4; nj++) {
            int n = bn + wn + nj * 16 + lr;
            if (n < 2048) {
                unsigned short* dst = (n < 1024) ? qb : kb;
                int n2 = n & 1023;
                int h = n2 >> 6, d = n2 & 63;
                size_t base = ((size_t)((bb << 4) + h) * T_ + t) * DH_ + d;
#pragma unroll
                for (int rr = 0; rr < 4; rr++)
                    dst[base + (size_t)rr * DH_] = f2bf(acc[mi][nj][rr]);
            } else {
                int n2 = n - 2048;
                int h = n2 >> 6, d = n2 & 63;
                // V^T layout [b][h][d][t]; 4 consecutive t in one 8B store
                size_t base = ((size_t)((bb << 4) + h) * DH_ + d) * T_ + t;
                union { unsigned short h4[4]; uint2 u; } pk;
#pragma unroll
                for (int rr = 0; rr < 4; rr++) pk.h4[rr] = f2bf(acc[mi][nj][rr]);
                *reinterpret_cast<uint2*>(vt + base) = pk.u;
            }
        }
    }
}

// -------------------- flash attention + fused output projection ------------
// grid = B*H*(T/64) = 1024 blocks; 4 waves = 2 q-waves(32 rows) x 2 key-grps.
// Scores in exp2 domain (LOG2E folded into Wq).  Static softmax (m=0).
// Double buffer, ONE barrier per KV tile + one post-loop barrier.
__global__ __launch_bounds__(256, 4) void attn_kernel(const unsigned short* __restrict__ qb,
                                                      const unsigned short* __restrict__ kbp,
                                                      const unsigned short* __restrict__ vt,
                                                      const unsigned short* __restrict__ wot,
                                                      const float* __restrict__ bo,
                                                      float* __restrict__ out) {
    // LDS map (bytes):
    //   [0,16384)     buf0: Ks[64][64] (8K) + Vs[64][64] (8K)
    //   [16384,32768) buf1: same
    //   epilogue aliases (all writes AFTER the post-loop barrier):
    //     Oex f32[2][32][64] @0 ; Olds bf16[2][32][64] @16384 ;
    //     Ls f32[2][32] @24576
    __shared__ __align__(16) char smem[32768];

    const int tid  = threadIdx.x;
    const int lane = tid & 63;
    const int wv   = tid >> 6;           // 0..3
    const int wq   = wv & 1, kg = wv >> 1;
    const int L    = lane & 31, hh = lane >> 5;
    const int kswz = L & 7;

    const int bid = (int)blockIdx.x;
    const int blk = (bid & 7) * 128 + (bid >> 3);  // XCD-chunked swizzle (1024/8)
    const int qt = blk & 31, bh = blk >> 5;        // 32 q-tiles of 64 rows
    const int b = bh >> 4, h = bh & 15;

    const unsigned short* Qp  = qb  + (size_t)bh * (T_ * DH_);
    const unsigned short* Kp  = kbp + (size_t)bh * (T_ * DH_);
    const unsigned short* Vtp = vt  + (size_t)bh * (DH_ * T_);

    // ---- Q fragments (B-operand: n=q=L, k = 16kc+8hh+j) ----
    const int qrow0 = qt * 64 + wq * 32;
    bf16x8 qf[4];
#pragma unroll
    for (int kc = 0; kc < 4; ++kc)
        qf[kc] = *reinterpret_cast<const bf16x8*>(
            Qp + (size_t)(qrow0 + L) * DH_ + kc * 16 + hh * 8);

    // ---- staging: all 4 waves; K rows wv*16..+16, V d-rows wv*16..+16 ----
    auto stage = [&](int bufsel, int kt0) {
        char* base = smem + bufsel * 16384;
        const int r8 = lane >> 3;
        const int c  = (lane & 7) ^ r8;       // row&7 == r8 for all rows below
#pragma unroll
        for (int g = 0; g < 2; ++g) {
            int row = wv * 16 + g * 8 + r8;   // K: key row
            gll16(Kp + ((size_t)(kt0 + row) << 6) + (c << 3),
                  base + (wv * 16 + g * 8) * 128);
        }
#pragma unroll
        for (int g = 0; g < 2; ++g) {
            int d = wv * 16 + g * 8 + r8;     // V: d row
            gll16(Vtp + ((size_t)d << 11) + kt0 + (c << 3),
                  base + 8192 + (wv * 16 + g * 8) * 128);
        }
    };

    f32x16 o0 = {}, o1 = {};
    float lpv[4] = {0.f, 0.f, 0.f, 0.f};   // 4-way partial row-sum

    stage(0, 0);   // prologue: tile 0 in flight

    const int NT = T_ / 64;   // 32 tiles
    for (int it = 0; it < NT; ++it) {
        const int cur = it & 1;
        // vmcnt(0): stage(it)'s loads (issued a full iteration ago) landed.
        // lgkmcnt(0): this wave's ds_reads of the buffer about to be restaged
        // retired (rule #18 guard for the single-barrier protocol).
        asm volatile("s_waitcnt vmcnt(0) lgkmcnt(0)" ::: "memory");
        __builtin_amdgcn_sched_barrier(0);
        __builtin_amdgcn_s_barrier();
        __builtin_amdgcn_sched_barrier(0);

        if (it + 1 < NT)   // stage tile it+1 into the buffer read at it-1;
            stage(cur ^ 1, (it + 1) * 64);   // its loads fly under compute

        const char* KB = smem + cur * 16384;
        const char* VB = KB + 8192;

        // ---- S^T = K * Q^T  (this key-group's 32 keys) ----
        f32x16 s = {};
        __builtin_amdgcn_s_setprio(1);
#pragma unroll
        for (int kc = 0; kc < 4; ++kc) {
            bf16x8 ka = *reinterpret_cast<const bf16x8*>(
                KB + (kg * 32 + L) * 128 + (((kc * 2 + hh) ^ kswz) << 4));
            s = MFMA32(ka, qf[kc], s);
        }
        __builtin_amdgcn_s_setprio(0);

        // ---- static softmax: P = exp2(S); partial row-sums ----
#pragma unroll
        for (int r = 0; r < 16; ++r) {
            s[r] = __builtin_amdgcn_exp2f(s[r]);
            lpv[r & 3] += s[r];
        }

        // ---- pack P to A-frags (cvt_pk + permlane32_swap), PV MFMAs ----
        __builtin_amdgcn_s_setprio(1);
#pragma unroll
        for (int kc = 0; kc < 2; ++kc) {
            unsigned X, X2, Y, Y2;
            asm("v_cvt_pk_bf16_f32 %0, %1, %2" : "=v"(X)  : "v"(s[kc * 8 + 0]), "v"(s[kc * 8 + 1]));
            asm("v_cvt_pk_bf16_f32 %0, %1, %2" : "=v"(X2) : "v"(s[kc * 8 + 2]), "v"(s[kc * 8 + 3]));
            asm("v_cvt_pk_bf16_f32 %0, %1, %2" : "=v"(Y)  : "v"(s[kc * 8 + 4]), "v"(s[kc * 8 + 5]));
            asm("v_cvt_pk_bf16_f32 %0, %1, %2" : "=v"(Y2) : "v"(s[kc * 8 + 6]), "v"(s[kc * 8 + 7]));
            asm("v_permlane32_swap_b32 %0, %1" : "+v"(X),  "+v"(Y));
            asm("v_permlane32_swap_b32 %0, %1" : "+v"(X2), "+v"(Y2));
            union { unsigned w[4]; bf16x8 v; } pa;
            pa.w[0] = X; pa.w[1] = X2; pa.w[2] = Y; pa.w[3] = Y2;
            const int gc = kg * 4 + kc * 2 + hh;   // key chunk (of 8)
            bf16x8 vf0 = *reinterpret_cast<const bf16x8*>(
                VB + L * 128 + ((gc ^ kswz) << 4));
            bf16x8 vf1 = *reinterpret_cast<const bf16x8*>(
                VB + (32 + L) * 128 + ((gc ^ kswz) << 4));
            o0 = MFMA32(pa.v, vf0, o0);
            o1 = MFMA32(pa.v, vf1, o1);
        }
        __builtin_amdgcn_s_setprio(0);
        // no trailing barrier: next iteration's barrier closes the phase
    }

    // ---- POST-LOOP BARRIER: all waves' iter-31 LDS reads must retire before
    // the epilogue overwrites buf regions (Ls aliases buf1's V).
    asm volatile("s_waitcnt vmcnt(0) lgkmcnt(0)" ::: "memory");
    __builtin_amdgcn_sched_barrier(0);
    __builtin_amdgcn_s_barrier();
    __builtin_amdgcn_sched_barrier(0);

    // ---- epilogue: combine key-groups, normalize, Y = O@Wo + bo ----
    float lp = (lpv[0] + lpv[1]) + (lpv[2] + lpv[3]);
    float l2 = lp + __shfl_xor(lp, 32);          // hh-combine: kg row-sum

    float* Oex = (float*)smem;                              // [2][32][64] (buf0)
    unsigned short* Olds = (unsigned short*)(smem + 16384); // [2][32][64] (buf1)
    float* Ls = (float*)(smem + 24576);                     // [2][32]

    if (kg == 1) {
        if (lane < 32) Ls[wq * 32 + L] = l2;
#pragma unroll
        for (int g = 0; g < 4; ++g)
#pragma unroll
            for (int c = 0; c < 4; ++c) {
                int qr = c + 8 * g + 4 * hh;
                Oex[(wq * 32 + qr) * 64 + L]      = o0[g * 4 + c];
                Oex[(wq * 32 + qr) * 64 + 32 + L] = o1[g * 4 + c];
            }
    }
    asm volatile("s_waitcnt lgkmcnt(0)" ::: "memory");
    __builtin_amdgcn_sched_barrier(0);
    __builtin_amdgcn_s_barrier();
    __builtin_amdgcn_sched_barrier(0);
    if (kg == 1) return;

    // Wo^T B-fragments straight from global (L2-hot: 8KB/head x 32 blocks)
    bf16x8 wf0[4], wf1[4];
#pragma unroll
    for (int kc = 0; kc < 4; ++kc) {
        int ko = (kc * 2 + hh) * 8;
        wf0[kc] = *reinterpret_cast<const bf16x8*>(
            wot + ((size_t)h << 12) + (L << 6) + ko);
        wf1[kc] = *reinterpret_cast<const bf16x8*>(
            wot + ((size_t)h << 12) + ((32 + L) << 6) + ko);
    }

    float ltot = l2 + Ls[wq * 32 + L];
    float invq = 1.f / ltot;
    if (lane < 32) Ls[wq * 32 + L] = invq;       // same-wave DS in-order

    // combine + normalize -> Olds (bf16, XOR-swizzled rows for A-frag reads)
#pragma unroll
    for (int g = 0; g < 4; ++g)
#pragma unroll
        for (int c = 0; c < 4; ++c) {
            int qr = c + 8 * g + 4 * hh;
            float ir = Ls[wq * 32 + qr];
            float v0 = (o0[g * 4 + c] + Oex[(wq * 32 + qr) * 64 + L]) * ir;
            float v1 = (o1[g * 4 + c] + Oex[(wq * 32 + qr) * 64 + 32 + L]) * ir;
            int c0 = (L >> 3) ^ (qr & 7);
            int c1 = (4 + (L >> 3)) ^ (qr & 7);
            Olds[(wq * 32 + qr) * 64 + c0 * 8 + (L & 7)] = f2bf(v0);
            Olds[(wq * 32 + qr) * 64 + c1 * 8 + (L & 7)] = f2bf(v1);
        }

    // Y = O @ Wo[h]  (A = O from Olds, B = Wo^T frags from global)
    f32x16 y0 = {}, y1 = {};
    const char* OB = (const char*)(smem + 16384) + wq * 4096;
#pragma unroll
    for (int kc = 0; kc < 4; ++kc) {
        int ch = ((kc * 2 + hh) ^ kswz) << 4;
        bf16x8 oa = *reinterpret_cast<const bf16x8*>(OB + L * 128 + ch);
        y0 = MFMA32(oa, wf0[kc], y0);
        y1 = MFMA32(oa, wf1[kc], y1);
    }

    float bias0 = bo[(h << 6) + L];
    float bias1 = bo[(h << 6) + 32 + L];
#pragma unroll
    for (int g = 0; g < 4; ++g)
#pragma unroll
        for (int c = 0; c < 4; ++c) {
            int t = qrow0 + c + 8 * g + 4 * hh;
            float* op = out + ((size_t)(b * T_ + t) << 10) + (h << 6);
            op[L]      = y0[g * 4 + c] + bias0;
            op[32 + L] = y1[g * 4 + c] + bias1;
        }
}

// ---------------------------------------------------------------------------
extern "C" void kernel_launch(void* const* d_in, const int* in_sizes, int n_in,
                              void* d_out, int out_size, void* d_ws, size_t ws_size,
                              hipStream_t stream) {
    const float* x   = (const float*)d_in[0];
    const float* Wq  = (const float*)d_in[1];
    const float* Wkv = (const float*)d_in[2];
    const float* Wo  = (const float*)d_in[3];
    const float* bo  = (const float*)d_in[4];
    float* out = (float*)d_out;

    char* ws = (char*)d_ws;
    unsigned short* xb  = (unsigned short*)(ws);                  //  8 MB  x bf16
    unsigned short* wt  = (unsigned short*)(ws + 8388608);        //  6 MB  [Wq^T;Wkv^T]
    unsigned short* wot = (unsigned short*)(ws + 14680064);       // 128 KB Wo^T
    unsigned short* qb  = (unsigned short*)(ws + 14811136);       //  8 MB  Q   [b][h][t][d]
    unsigned short* kb  = (unsigned short*)(ws + 23199744);       //  8 MB  K   [b][h][t][d]
    unsigned short* vt  = (unsigned short*)(ws + 31588352);       //  8 MB  V^T [b][h][d][t]

    // fused prep: cvt_x (4096) | cvt_wo (256) | Wq^T (1024) | Wkv^T (2048)
    prep_kernel<<<7424, 256, 0, stream>>>(x, Wq, Wkv, Wo, xb, wt, wot);
    qkv_gemm_kernel<<<768, 256, 0, stream>>>(xb, wt, qb, kb, vt);
    attn_kernel<<<1024, 256, 0, stream>>>(qb, kb, vt, wot, bo, out);
}